// Round 3
// baseline (2143.959 us; speedup 1.0000x reference)
//
#include <hip/hip_runtime.h>
#include <hip/hip_bf16.h>

// Problem constants
#define B_   2
#define S_   2048
#define D_   1024
#define H_   16
#define L_   4
#define DK_  64
#define DFF_ 4096
#define V_   2000

typedef __bf16 bf16x8 __attribute__((ext_vector_type(8)));
typedef float  f32x4  __attribute__((ext_vector_type(4)));
typedef __attribute__((address_space(1))) const void* as1cv;
typedef __attribute__((address_space(3))) void* as3v;

__device__ __forceinline__ void async_copy16(const void* g, void* l) {
    __builtin_amdgcn_global_load_lds((as1cv)g, (as3v)l, 16, 0, 0);
}

// ---------------------------------------------------------------------------
// Canonicalize a tensor to bf16 (device-side dtype probe: ln1_w first u16).
// ---------------------------------------------------------------------------
__global__ __launch_bounds__(256)
void canon_k(const void* __restrict__ src, __hip_bfloat16* __restrict__ dst,
             long n, const unsigned short* __restrict__ probe)
{
    const bool isbf = (probe[0] == 0x3F80u);
    long i0 = ((long)blockIdx.x * 256 + threadIdx.x) * 8;
    if (isbf) {
        const __hip_bfloat16* s = (const __hip_bfloat16*)src;
        #pragma unroll
        for (int j = 0; j < 8; ++j) { long i = i0 + j; if (i < n) dst[i] = s[i]; }
    } else {
        const float* s = (const float*)src;
        #pragma unroll
        for (int j = 0; j < 8; ++j) { long i = i0 + j; if (i < n) dst[i] = __float2bfloat16(s[i]); }
    }
}

// ---------------------------------------------------------------------------
// GEMM: Out[m,n] = sum_k A[m,k] * W[n,k]
// MODE 0: bf16.  MODE 1: fp32 += Res(bf16).  MODE 2: bf16 relu.
// MODE 3: probe-dtyped output (final logits).  MODE 5: fused QKV, z=2 writes
//         V^T scattered as [b][h][dk][s] (bf16).
// TM: 128 -> 128x128 tile (4 waves 2x2); 64 -> 64x128 tile (4 waves 1x4,
//     doubles block count for narrow-N GEMMs).
// ---------------------------------------------------------------------------
template<int MODE, int TM>
__global__ __launch_bounds__(256, 2)
void gemm_bt(const __hip_bfloat16* __restrict__ A,
             const __hip_bfloat16* __restrict__ Wa,
             const __hip_bfloat16* __restrict__ Wb,
             const __hip_bfloat16* __restrict__ Wc,
             void* __restrict__ Oa, void* __restrict__ Obp, void* __restrict__ Ocp,
             const __hip_bfloat16* __restrict__ Res,
             const unsigned short* __restrict__ probe,
             int M, int N, int K)
{
    const __hip_bfloat16* W = Wa;
    void* Out = Oa;
    if (MODE == 5) {
        if (blockIdx.z == 1) { W = Wb; Out = Obp; }
        else if (blockIdx.z == 2) { W = Wc; Out = Ocp; }
    }

    constexpr int NJ = (TM == 128) ? 4 : 2;
    __shared__ __bf16 As[TM * 32];
    __shared__ __bf16 Bs[128 * 32];

    const int tid  = threadIdx.x;
    const int wave = tid >> 6;
    const int lane = tid & 63;
    const int quad = lane >> 4;
    const int l16  = lane & 15;
    const int bm = blockIdx.x;
    const int bn = blockIdx.y;
    const int wm = (TM == 128) ? (wave >> 1) * 64 : 0;
    const int wn = (TM == 128) ? (wave & 1) * 64 : wave * 32;

    const int sr = tid >> 2;
    const int sc = (tid & 3) * 8;
    const __hip_bfloat16* ap0 = A + (long)(bm * TM + sr) * K + sc;
    const __hip_bfloat16* ap1 = ap0 + (long)64 * K;   // used only if TM==128
    const __hip_bfloat16* bp0 = W + (long)(bn * 128 + sr) * K + sc;
    const __hip_bfloat16* bp1 = bp0 + (long)64 * K;
    const bool bok0 = (bn * 128 + sr) < N;
    const bool bok1 = (bn * 128 + sr + 64) < N;

    __bf16* aL0 = As + wave * 512;
    __bf16* aL1 = As + 2048 + wave * 512;
    __bf16* bL0 = Bs + wave * 512;
    __bf16* bL1 = Bs + 2048 + wave * 512;

    if (N & 127) {   // defensive zero for tail columns (logits GEMM)
        #pragma unroll
        for (int j = 0; j < 2; ++j)
            *(bf16x8*)(Bs + (j * 256 + tid) * 8) = (bf16x8)0;
        __syncthreads();
    }

    f32x4 acc[4][NJ] = {};

    for (int k0 = 0; k0 < K; k0 += 32) {
        async_copy16(ap0 + k0, aL0);
        if (TM == 128) async_copy16(ap1 + k0, aL1);
        if (bok0) async_copy16(bp0 + k0, bL0);
        if (bok1) async_copy16(bp1 + k0, bL1);
        __syncthreads();

        bf16x8 af[4], bfr[NJ];
        #pragma unroll
        for (int i = 0; i < 4; ++i)
            af[i] = *(const bf16x8*)(As + (wm + i * 16 + l16) * 32 + quad * 8);
        #pragma unroll
        for (int j = 0; j < NJ; ++j)
            bfr[j] = *(const bf16x8*)(Bs + (wn + j * 16 + l16) * 32 + quad * 8);
        #pragma unroll
        for (int i = 0; i < 4; ++i)
            #pragma unroll
            for (int j = 0; j < NJ; ++j)
                acc[i][j] = __builtin_amdgcn_mfma_f32_16x16x32_bf16(af[i], bfr[j], acc[i][j], 0, 0, 0);
        __syncthreads();
    }

    const bool out_bf = (MODE != 1) && (MODE != 3 || probe[0] == 0x3F80u);
    const bool vscat  = (MODE == 5) && (blockIdx.z == 2);
    #pragma unroll
    for (int i = 0; i < 4; ++i) {
        #pragma unroll
        for (int r = 0; r < 4; ++r) {
            const long row = bm * TM + wm + i * 16 + quad * 4 + r;
            #pragma unroll
            for (int j = 0; j < NJ; ++j) {
                const int col = bn * 128 + wn + j * 16 + l16;
                if (col < N) {
                    float v = acc[i][j][r];
                    if (vscat) {
                        // V^T: [b][h][dk][s]
                        const long vtidx = ((long)((row >> 11) * H_ + (col >> 6)) * DK_ + (col & 63)) * S_ + (row & (S_ - 1));
                        ((__hip_bfloat16*)Out)[vtidx] = __float2bfloat16(v);
                    } else {
                        const long idx = row * (long)N + col;
                        if constexpr (MODE == 1) {
                            ((float*)Out)[idx] = v + __bfloat162float(Res[idx]);
                        } else if constexpr (MODE == 2) {
                            ((__hip_bfloat16*)Out)[idx] = __float2bfloat16(v > 0.f ? v : 0.f);
                        } else {
                            if (out_bf) ((__hip_bfloat16*)Out)[idx] = __float2bfloat16(v);
                            else        ((float*)Out)[idx] = v;
                        }
                    }
                }
            }
        }
    }
}

// ---------------------------------------------------------------------------
// Flash attention, causal, BARRIER-FREE kv loop.
// Q/K read from token-major [B*S][D]; V from precomputed V^T [B][H][DK][S].
// Grid (32, H, B), 256 thr (4 waves; wave owns 16 q rows). qt reversed so
// heavy (late) q-tiles dispatch first -> causal load balance.
// Only LDS: wave-private P relayout buffer (C->A), in-order DS per wave.
// ---------------------------------------------------------------------------
__global__ __launch_bounds__(256, 4)
void flash_attn(const __hip_bfloat16* __restrict__ Qg,
                const __hip_bfloat16* __restrict__ Kg,
                const __hip_bfloat16* __restrict__ VTg,
                __hip_bfloat16* __restrict__ Og)
{
    const int qt = 31 - blockIdx.x;
    const int h  = blockIdx.y;
    const int b  = blockIdx.z;
    const int tid  = threadIdx.x;
    const int wave = tid >> 6;
    const int lane = tid & 63;
    const int quad = lane >> 4;
    const int l16  = lane & 15;

    __shared__ __bf16 Ps[4][16 * 72];

    const long qk_base = ((long)b * S_) * D_ + h * DK_;
    const long vt_base = ((long)(b * H_ + h)) * DK_ * S_;
    const int  q0 = qt * 64 + wave * 16;

    // Q A-fragments, straight from global (held in regs for whole kernel)
    const __hip_bfloat16* qp = Qg + qk_base + (long)(q0 + l16) * D_ + quad * 8;
    const bf16x8 qf0 = *(const bf16x8*)qp;
    const bf16x8 qf1 = *(const bf16x8*)(qp + 32);

    f32x4 o_acc[4] = {};
    float m_run[4], l_run[4];
    #pragma unroll
    for (int r = 0; r < 4; ++r) { m_run[r] = -1e30f; l_run[r] = 0.f; }

    const float scl2 = 0.18033688011112042f;  // (1/sqrt(64)) * log2(e)
    const int q_base = q0 + quad * 4;

    for (int kv0 = 0; kv0 <= qt * 64; kv0 += 64) {
        // S = Q K^T  (K B-fragments direct from global, 16 rows x 64B)
        f32x4 sAcc[4] = {};
        #pragma unroll
        for (int nt = 0; nt < 4; ++nt) {
            const __hip_bfloat16* kp = Kg + qk_base + (long)(kv0 + nt * 16 + l16) * D_ + quad * 8;
            sAcc[nt] = __builtin_amdgcn_mfma_f32_16x16x32_bf16(qf0, *(const bf16x8*)kp,        sAcc[nt], 0, 0, 0);
            sAcc[nt] = __builtin_amdgcn_mfma_f32_16x16x32_bf16(qf1, *(const bf16x8*)(kp + 32), sAcc[nt], 0, 0, 0);
        }

        // prefetch V^T B-fragments; latency overlaps the softmax below
        bf16x8 vf[4][2];
        #pragma unroll
        for (int nt = 0; nt < 4; ++nt) {
            const __hip_bfloat16* vp = VTg + vt_base + (long)(nt * 16 + l16) * S_ + kv0 + quad * 8;
            vf[nt][0] = *(const bf16x8*)vp;
            vf[nt][1] = *(const bf16x8*)(vp + 32);
        }

        const bool diag = (kv0 == qt * 64);
        float rmax[4];
        #pragma unroll
        for (int r = 0; r < 4; ++r) rmax[r] = -1e30f;
        #pragma unroll
        for (int nt = 0; nt < 4; ++nt)
            #pragma unroll
            for (int r = 0; r < 4; ++r) {
                float s = sAcc[nt][r] * scl2;
                if (diag && (kv0 + nt * 16 + l16) > (q_base + r)) s = -1e30f;
                sAcc[nt][r] = s;
                rmax[r] = fmaxf(rmax[r], s);
            }
        #pragma unroll
        for (int off = 1; off < 16; off <<= 1)
            #pragma unroll
            for (int r = 0; r < 4; ++r)
                rmax[r] = fmaxf(rmax[r], __shfl_xor(rmax[r], off, 64));

        float alpha[4];
        #pragma unroll
        for (int r = 0; r < 4; ++r) {
            const float mn = fmaxf(m_run[r], rmax[r]);
            alpha[r] = __builtin_exp2f(m_run[r] - mn);
            m_run[r] = mn;
            l_run[r] *= alpha[r];   // per-lane partial sum; reduced at the end
        }
        #pragma unroll
        for (int nt = 0; nt < 4; ++nt)
            #pragma unroll
            for (int r = 0; r < 4; ++r) {
                const float p = __builtin_exp2f(sAcc[nt][r] - m_run[r]);
                sAcc[nt][r] = p;
                l_run[r] += p;
            }
        #pragma unroll
        for (int nt = 0; nt < 4; ++nt)
            #pragma unroll
            for (int r = 0; r < 4; ++r) o_acc[nt][r] *= alpha[r];

        // P: C-layout -> LDS -> A-layout (wave-private buffer, DS in-order)
        __bf16* pw = &Ps[wave][0];
        #pragma unroll
        for (int nt = 0; nt < 4; ++nt)
            #pragma unroll
            for (int r = 0; r < 4; ++r)
                pw[(quad * 4 + r) * 72 + nt * 16 + l16] = (__bf16)sAcc[nt][r];
        asm volatile("" ::: "memory");
        const __bf16* pb = pw + l16 * 72 + quad * 8;
        const bf16x8 pf0 = *(const bf16x8*)pb;
        const bf16x8 pf1 = *(const bf16x8*)(pb + 32);
        #pragma unroll
        for (int nt = 0; nt < 4; ++nt) {
            o_acc[nt] = __builtin_amdgcn_mfma_f32_16x16x32_bf16(pf0, vf[nt][0], o_acc[nt], 0, 0, 0);
            o_acc[nt] = __builtin_amdgcn_mfma_f32_16x16x32_bf16(pf1, vf[nt][1], o_acc[nt], 0, 0, 0);
        }
    }

    // reduce per-lane partial l across the 16 lanes of the quad
    #pragma unroll
    for (int off = 1; off < 16; off <<= 1)
        #pragma unroll
        for (int r = 0; r < 4; ++r)
            l_run[r] += __shfl_xor(l_run[r], off, 64);

    #pragma unroll
    for (int nt = 0; nt < 4; ++nt)
        #pragma unroll
        for (int r = 0; r < 4; ++r) {
            const long row = (long)b * S_ + q0 + quad * 4 + r;
            const int col = h * DK_ + nt * 16 + l16;
            Og[row * D_ + col] = __float2bfloat16(o_acc[nt][r] / l_run[r]);
        }
}

// ---------------------------------------------------------------------------
__global__ __launch_bounds__(256)
void layernorm_k(const float* __restrict__ in,
                 const __hip_bfloat16* __restrict__ w,
                 const __hip_bfloat16* __restrict__ bb,
                 __hip_bfloat16* __restrict__ out)
{
    const int row = blockIdx.x;
    const int tid = threadIdx.x;
    const float4 v = ((const float4*)(in + (long)row * D_))[tid];
    float s  = v.x + v.y + v.z + v.w;
    float ss = v.x * v.x + v.y * v.y + v.z * v.z + v.w * v.w;
    #pragma unroll
    for (int off = 1; off < 64; off <<= 1) {
        s  += __shfl_xor(s, off, 64);
        ss += __shfl_xor(ss, off, 64);
    }
    __shared__ float red[8];
    if ((tid & 63) == 0) { red[tid >> 6] = s; red[4 + (tid >> 6)] = ss; }
    __syncthreads();
    s  = red[0] + red[1] + red[2] + red[3];
    ss = red[4] + red[5] + red[6] + red[7];
    const float mean = s * (1.f / D_);
    const float var  = ss * (1.f / D_) - mean * mean;
    const float rs = rsqrtf(var + 1e-5f);
    const int d0 = tid * 4;
    const float xs[4] = { v.x, v.y, v.z, v.w };
    #pragma unroll
    for (int j = 0; j < 4; ++j) {
        const float wv = __bfloat162float(w[d0 + j]);
        const float bv = __bfloat162float(bb[d0 + j]);
        out[(long)row * D_ + d0 + j] = __float2bfloat16((xs[j] - mean) * rs * wv + bv);
    }
}

__global__ __launch_bounds__(256)
void embed_k(const int* __restrict__ idx,
             const __hip_bfloat16* __restrict__ emb,
             __hip_bfloat16* __restrict__ X)
{
    const int row = blockIdx.x;
    const int s = row & (S_ - 1);
    const int tid = threadIdx.x;
    const int token = idx[row];
    const __hip_bfloat16* e = emb + (long)token * D_;
    #pragma unroll
    for (int j = 0; j < 4; ++j) {
        const int d = tid + j * 256;
        const float di = (float)(d & ~1);
        const float freq = __expf(di * (-9.210340371976184f / (float)D_));
        const float angle = (float)s * freq;
        const float pe = (d & 1) ? cosf(angle) : sinf(angle);
        X[(long)row * D_ + d] = __float2bfloat16(__bfloat162float(e[d]) + pe);
    }
}

// ---------------------------------------------------------------------------
extern "C" void kernel_launch(void* const* d_in, const int* in_sizes, int n_in,
                              void* d_out, int out_size, void* d_ws, size_t ws_size,
                              hipStream_t stream)
{
    const int* indices = (const int*)d_in[0];
    const unsigned short* probe = (const unsigned short*)d_in[6];  // ln1_w (ones)

    const long NTOK = (long)B_ * S_;   // 4096
    char* ws = (char*)d_ws;
    __hip_bfloat16* X  = (__hip_bfloat16*)ws; ws += NTOK * D_ * 2;
    __hip_bfloat16* Qb = (__hip_bfloat16*)ws; ws += NTOK * D_ * 2;
    __hip_bfloat16* Kb = (__hip_bfloat16*)ws; ws += NTOK * D_ * 2;
    __hip_bfloat16* VT = (__hip_bfloat16*)ws; ws += NTOK * D_ * 2;   // [B][H][DK][S]
    __hip_bfloat16* Ob = (__hip_bfloat16*)ws; ws += NTOK * D_ * 2;
    __hip_bfloat16* Hb = Qb;  // FFN hidden aliases Qb..Ob (32MB), disjoint lifetime
    float* tmp = (float*)ws;                  ws += NTOK * D_ * 4;
    __hip_bfloat16* cEmb  = (__hip_bfloat16*)ws; ws += (long)V_ * D_ * 2;
    __hip_bfloat16* cWq   = (__hip_bfloat16*)ws; ws += (long)L_ * D_ * D_ * 2;
    __hip_bfloat16* cWk   = (__hip_bfloat16*)ws; ws += (long)L_ * D_ * D_ * 2;
    __hip_bfloat16* cWv   = (__hip_bfloat16*)ws; ws += (long)L_ * D_ * D_ * 2;
    __hip_bfloat16* cWo   = (__hip_bfloat16*)ws; ws += (long)L_ * D_ * D_ * 2;
    __hip_bfloat16* cW1   = (__hip_bfloat16*)ws; ws += (long)L_ * DFF_ * D_ * 2;
    __hip_bfloat16* cW2   = (__hip_bfloat16*)ws; ws += (long)L_ * D_ * DFF_ * 2;
    __hip_bfloat16* cWout = (__hip_bfloat16*)ws; ws += (long)V_ * D_ * 2;
    __hip_bfloat16* cLn1w = (__hip_bfloat16*)ws; ws += (long)L_ * D_ * 2;
    __hip_bfloat16* cLn1b = (__hip_bfloat16*)ws; ws += (long)L_ * D_ * 2;
    __hip_bfloat16* cLn2w = (__hip_bfloat16*)ws; ws += (long)L_ * D_ * 2;
    __hip_bfloat16* cLn2b = (__hip_bfloat16*)ws; ws += (long)L_ * D_ * 2;

    struct { const void* src; __hip_bfloat16* dst; long n; } cv[12] = {
        { d_in[1],  cEmb,  (long)V_ * D_ },
        { d_in[2],  cWq,   (long)L_ * D_ * D_ },
        { d_in[3],  cWk,   (long)L_ * D_ * D_ },
        { d_in[4],  cWv,   (long)L_ * D_ * D_ },
        { d_in[5],  cWo,   (long)L_ * D_ * D_ },
        { d_in[6],  cLn1w, (long)L_ * D_ },
        { d_in[7],  cLn1b, (long)L_ * D_ },
        { d_in[8],  cW1,   (long)L_ * DFF_ * D_ },
        { d_in[9],  cW2,   (long)L_ * D_ * DFF_ },
        { d_in[10], cLn2w, (long)L_ * D_ },
        { d_in[11], cLn2b, (long)L_ * D_ },
        { d_in[12], cWout, (long)V_ * D_ },
    };
    for (int i = 0; i < 12; ++i) {
        const long blocks = (cv[i].n + 2047) / 2048;
        canon_k<<<dim3((unsigned)blocks), 256, 0, stream>>>(cv[i].src, cv[i].dst, cv[i].n, probe);
    }

    embed_k<<<dim3(NTOK), 256, 0, stream>>>(indices, cEmb, X);

    for (int l = 0; l < L_; ++l) {
        const __hip_bfloat16* wq = cWq + (long)l * D_ * D_;
        const __hip_bfloat16* wk = cWk + (long)l * D_ * D_;
        const __hip_bfloat16* wv = cWv + (long)l * D_ * D_;
        const __hip_bfloat16* wo = cWo + (long)l * D_ * D_;
        const __hip_bfloat16* w1 = cW1 + (long)l * DFF_ * D_;
        const __hip_bfloat16* w2 = cW2 + (long)l * D_ * DFF_;

        // fused QKV; z=2 (V) writes V^T
        gemm_bt<5, 128><<<dim3(32, 8, 3), 256, 0, stream>>>(X, wq, wk, wv, Qb, Kb, VT, nullptr, nullptr, 4096, 1024, 1024);
        flash_attn<<<dim3(32, 16, 2), 256, 0, stream>>>(Qb, Kb, VT, Ob);
        gemm_bt<1, 64><<<dim3(64, 8, 1), 256, 0, stream>>>(Ob, wo, wo, wo, tmp, tmp, tmp, X, nullptr, 4096, 1024, 1024);
        layernorm_k<<<dim3(4096), 256, 0, stream>>>(tmp, cLn1w + l * D_, cLn1b + l * D_, X);
        gemm_bt<2, 128><<<dim3(32, 32, 1), 256, 0, stream>>>(X, w1, w1, w1, Hb, Hb, Hb, nullptr, nullptr, 4096, 4096, 1024);
        gemm_bt<1, 64><<<dim3(64, 8, 1), 256, 0, stream>>>(Hb, w2, w2, w2, tmp, tmp, tmp, X, nullptr, 4096, 1024, 4096);
        layernorm_k<<<dim3(4096), 256, 0, stream>>>(tmp, cLn2w + l * D_, cLn2b + l * D_, X);
    }

    gemm_bt<3, 128><<<dim3(32, 16, 1), 256, 0, stream>>>(X, cWout, cWout, cWout, d_out, d_out, d_out, nullptr, probe, 4096, V_, 1024);
}

// Round 4
// 2126.889 us; speedup vs baseline: 1.0080x; 1.0080x over previous
//
#include <hip/hip_runtime.h>
#include <hip/hip_bf16.h>

// Problem constants
#define B_   2
#define S_   2048
#define D_   1024
#define H_   16
#define L_   4
#define DK_  64
#define DFF_ 4096
#define V_   2000

typedef __bf16 bf16x8 __attribute__((ext_vector_type(8)));
typedef float  f32x4  __attribute__((ext_vector_type(4)));
typedef __attribute__((address_space(1))) const void* as1cv;
typedef __attribute__((address_space(3))) void* as3v;

#define QSCALE 0.18033688011112042f   // (1/sqrt(64)) * log2(e), folded into Q

__device__ __forceinline__ void async_copy16(const void* g, void* l) {
    __builtin_amdgcn_global_load_lds((as1cv)g, (as3v)l, 16, 0, 0);
}

// ---------------------------------------------------------------------------
// Canonicalize a tensor to bf16 (device-side dtype probe: ln1_w first u16).
// ---------------------------------------------------------------------------
__global__ __launch_bounds__(256)
void canon_k(const void* __restrict__ src, __hip_bfloat16* __restrict__ dst,
             long n, const unsigned short* __restrict__ probe)
{
    const bool isbf = (probe[0] == 0x3F80u);
    long i0 = ((long)blockIdx.x * 256 + threadIdx.x) * 8;
    if (isbf) {
        const __hip_bfloat16* s = (const __hip_bfloat16*)src;
        #pragma unroll
        for (int j = 0; j < 8; ++j) { long i = i0 + j; if (i < n) dst[i] = s[i]; }
    } else {
        const float* s = (const float*)src;
        #pragma unroll
        for (int j = 0; j < 8; ++j) { long i = i0 + j; if (i < n) dst[i] = __float2bfloat16(s[i]); }
    }
}

// ---------------------------------------------------------------------------
// GEMM: Out[m,n] = sum_k A[m,k] * W[n,k]
// MODE 0: bf16.  MODE 1: fp32 += Res(bf16).  MODE 2: bf16 relu.
// MODE 3: probe-dtyped output (final logits).  MODE 5: fused QKV, z=0 scales
//         Q by QSCALE, z=2 writes V^T scattered as [b][h][dk][s].
// TM: 128 -> 128x128 tile (4 waves 2x2); 64 -> 64x128 tile (4 waves 1x4).
// ---------------------------------------------------------------------------
template<int MODE, int TM>
__global__ __launch_bounds__(256, 2)
void gemm_bt(const __hip_bfloat16* __restrict__ A,
             const __hip_bfloat16* __restrict__ Wa,
             const __hip_bfloat16* __restrict__ Wb,
             const __hip_bfloat16* __restrict__ Wc,
             void* __restrict__ Oa, void* __restrict__ Obp, void* __restrict__ Ocp,
             const __hip_bfloat16* __restrict__ Res,
             const unsigned short* __restrict__ probe,
             int M, int N, int K)
{
    const __hip_bfloat16* W = Wa;
    void* Out = Oa;
    if (MODE == 5) {
        if (blockIdx.z == 1) { W = Wb; Out = Obp; }
        else if (blockIdx.z == 2) { W = Wc; Out = Ocp; }
    }

    constexpr int NJ = (TM == 128) ? 4 : 2;
    __shared__ __bf16 As[TM * 32];
    __shared__ __bf16 Bs[128 * 32];

    const int tid  = threadIdx.x;
    const int wave = tid >> 6;
    const int lane = tid & 63;
    const int quad = lane >> 4;
    const int l16  = lane & 15;
    const int bm = blockIdx.x;
    const int bn = blockIdx.y;
    const int wm = (TM == 128) ? (wave >> 1) * 64 : 0;
    const int wn = (TM == 128) ? (wave & 1) * 64 : wave * 32;

    const int sr = tid >> 2;
    const int sc = (tid & 3) * 8;
    const __hip_bfloat16* ap0 = A + (long)(bm * TM + sr) * K + sc;
    const __hip_bfloat16* ap1 = ap0 + (long)64 * K;
    const __hip_bfloat16* bp0 = W + (long)(bn * 128 + sr) * K + sc;
    const __hip_bfloat16* bp1 = bp0 + (long)64 * K;
    const bool bok0 = (bn * 128 + sr) < N;
    const bool bok1 = (bn * 128 + sr + 64) < N;

    __bf16* aL0 = As + wave * 512;
    __bf16* aL1 = As + 2048 + wave * 512;
    __bf16* bL0 = Bs + wave * 512;
    __bf16* bL1 = Bs + 2048 + wave * 512;

    if (N & 127) {
        #pragma unroll
        for (int j = 0; j < 2; ++j)
            *(bf16x8*)(Bs + (j * 256 + tid) * 8) = (bf16x8)0;
        __syncthreads();
    }

    f32x4 acc[4][NJ] = {};

    for (int k0 = 0; k0 < K; k0 += 32) {
        async_copy16(ap0 + k0, aL0);
        if (TM == 128) async_copy16(ap1 + k0, aL1);
        if (bok0) async_copy16(bp0 + k0, bL0);
        if (bok1) async_copy16(bp1 + k0, bL1);
        __syncthreads();

        bf16x8 af[4], bfr[NJ];
        #pragma unroll
        for (int i = 0; i < 4; ++i)
            af[i] = *(const bf16x8*)(As + (wm + i * 16 + l16) * 32 + quad * 8);
        #pragma unroll
        for (int j = 0; j < NJ; ++j)
            bfr[j] = *(const bf16x8*)(Bs + (wn + j * 16 + l16) * 32 + quad * 8);
        #pragma unroll
        for (int i = 0; i < 4; ++i)
            #pragma unroll
            for (int j = 0; j < NJ; ++j)
                acc[i][j] = __builtin_amdgcn_mfma_f32_16x16x32_bf16(af[i], bfr[j], acc[i][j], 0, 0, 0);
        __syncthreads();
    }

    const bool out_bf = (MODE != 1) && (MODE != 3 || probe[0] == 0x3F80u);
    const bool vscat  = (MODE == 5) && (blockIdx.z == 2);
    const bool qscal  = (MODE == 5) && (blockIdx.z == 0);
    #pragma unroll
    for (int i = 0; i < 4; ++i) {
        #pragma unroll
        for (int r = 0; r < 4; ++r) {
            const long row = bm * TM + wm + i * 16 + quad * 4 + r;
            #pragma unroll
            for (int j = 0; j < NJ; ++j) {
                const int col = bn * 128 + wn + j * 16 + l16;
                if (col < N) {
                    float v = acc[i][j][r];
                    if (vscat) {
                        const long vtidx = ((long)((row >> 11) * H_ + (col >> 6)) * DK_ + (col & 63)) * S_ + (row & (S_ - 1));
                        ((__hip_bfloat16*)Out)[vtidx] = __float2bfloat16(v);
                    } else {
                        if (qscal) v *= QSCALE;
                        const long idx = row * (long)N + col;
                        if constexpr (MODE == 1) {
                            ((float*)Out)[idx] = v + __bfloat162float(Res[idx]);
                        } else if constexpr (MODE == 2) {
                            ((__hip_bfloat16*)Out)[idx] = __float2bfloat16(v > 0.f ? v : 0.f);
                        } else {
                            if (out_bf) ((__hip_bfloat16*)Out)[idx] = __float2bfloat16(v);
                            else        ((float*)Out)[idx] = v;
                        }
                    }
                }
            }
        }
    }
}

// ---------------------------------------------------------------------------
// Flash attention, causal, software-pipelined barrier-free kv loop.
// Q pre-scaled by QSCALE. K from [B*S][D]; V from V^T [B][H][DK][S].
// Grid (32, H, B) with qt reversed; 4 waves, wave owns 16 q rows.
// Rotated loop: K/V fragments for tile t+1 are loaded (into regs) right
// after tile t's consumers, giving a full iteration of latency cover.
// ---------------------------------------------------------------------------
__global__ __launch_bounds__(256, 3)
void flash_attn(const __hip_bfloat16* __restrict__ Qg,
                const __hip_bfloat16* __restrict__ Kg,
                const __hip_bfloat16* __restrict__ VTg,
                __hip_bfloat16* __restrict__ Og)
{
    const int qt = 31 - blockIdx.x;
    const int h  = blockIdx.y;
    const int b  = blockIdx.z;
    const int tid  = threadIdx.x;
    const int wave = tid >> 6;
    const int lane = tid & 63;
    const int quad = lane >> 4;
    const int l16  = lane & 15;

    __shared__ __bf16 Ps[4][16 * 72];

    const long qk_base = ((long)b * S_) * D_ + h * DK_;
    const long vt_base = ((long)(b * H_ + h)) * DK_ * S_;
    const int  q0 = qt * 64 + wave * 16;

    const __hip_bfloat16* qp = Qg + qk_base + (long)(q0 + l16) * D_ + quad * 8;
    const bf16x8 qf0 = *(const bf16x8*)qp;
    const bf16x8 qf1 = *(const bf16x8*)(qp + 32);

    // rolling per-lane base pointers (tile 0)
    const __hip_bfloat16* kp = Kg + qk_base + (long)l16 * D_ + quad * 8;
    const __hip_bfloat16* vp = VTg + vt_base + (long)l16 * S_ + quad * 8;

    bf16x8 kf[4][2], vfr[4][2];
    #pragma unroll
    for (int nt = 0; nt < 4; ++nt) {
        const __hip_bfloat16* k = kp + (long)nt * 16 * D_;
        kf[nt][0] = *(const bf16x8*)k;
        kf[nt][1] = *(const bf16x8*)(k + 32);
        const __hip_bfloat16* v = vp + (long)nt * 16 * S_;
        vfr[nt][0] = *(const bf16x8*)v;
        vfr[nt][1] = *(const bf16x8*)(v + 32);
    }

    f32x4 o_acc[4] = {};
    float m_run[4], l_run[4];
    #pragma unroll
    for (int r = 0; r < 4; ++r) { m_run[r] = -1e30f; l_run[r] = 0.f; }
    const int q_row = q0 + quad * 4;
    __bf16* pw = &Ps[wave][0];
    const __bf16* pb = pw + l16 * 72 + quad * 8;

    // main loop over non-diagonal tiles (t = 0 .. qt-1), diag tile peeled
    for (int t = 0; t < qt; ++t) {
        f32x4 sAcc[4] = {};
        #pragma unroll
        for (int nt = 0; nt < 4; ++nt) {
            sAcc[nt] = __builtin_amdgcn_mfma_f32_16x16x32_bf16(qf0, kf[nt][0], sAcc[nt], 0, 0, 0);
            sAcc[nt] = __builtin_amdgcn_mfma_f32_16x16x32_bf16(qf1, kf[nt][1], sAcc[nt], 0, 0, 0);
        }
        // prefetch K for tile t+1 (issued early, consumed next iteration)
        kp += (long)64 * D_;
        #pragma unroll
        for (int nt = 0; nt < 4; ++nt) {
            const __hip_bfloat16* k = kp + (long)nt * 16 * D_;
            kf[nt][0] = *(const bf16x8*)k;
            kf[nt][1] = *(const bf16x8*)(k + 32);
        }

        float rmax[4];
        #pragma unroll
        for (int r = 0; r < 4; ++r) rmax[r] = -1e30f;
        #pragma unroll
        for (int nt = 0; nt < 4; ++nt)
            #pragma unroll
            for (int r = 0; r < 4; ++r) rmax[r] = fmaxf(rmax[r], sAcc[nt][r]);
        #pragma unroll
        for (int off = 1; off < 16; off <<= 1)
            #pragma unroll
            for (int r = 0; r < 4; ++r)
                rmax[r] = fmaxf(rmax[r], __shfl_xor(rmax[r], off, 64));

        float alpha[4];
        #pragma unroll
        for (int r = 0; r < 4; ++r) {
            const float mn = fmaxf(m_run[r], rmax[r]);
            alpha[r] = __builtin_exp2f(m_run[r] - mn);
            m_run[r] = mn;
            l_run[r] *= alpha[r];
        }
        #pragma unroll
        for (int nt = 0; nt < 4; ++nt)
            #pragma unroll
            for (int r = 0; r < 4; ++r) {
                const float p = __builtin_exp2f(sAcc[nt][r] - m_run[r]);
                sAcc[nt][r] = p;
                l_run[r] += p;
            }
        #pragma unroll
        for (int nt = 0; nt < 4; ++nt)
            #pragma unroll
            for (int r = 0; r < 4; ++r) o_acc[nt][r] *= alpha[r];

        #pragma unroll
        for (int nt = 0; nt < 4; ++nt)
            #pragma unroll
            for (int r = 0; r < 4; ++r)
                pw[(quad * 4 + r) * 72 + nt * 16 + l16] = (__bf16)sAcc[nt][r];
        asm volatile("" ::: "memory");
        const bf16x8 pf0 = *(const bf16x8*)pb;
        const bf16x8 pf1 = *(const bf16x8*)(pb + 32);
        #pragma unroll
        for (int nt = 0; nt < 4; ++nt) {
            o_acc[nt] = __builtin_amdgcn_mfma_f32_16x16x32_bf16(pf0, vfr[nt][0], o_acc[nt], 0, 0, 0);
            o_acc[nt] = __builtin_amdgcn_mfma_f32_16x16x32_bf16(pf1, vfr[nt][1], o_acc[nt], 0, 0, 0);
        }
        // prefetch V for tile t+1
        vp += 64;
        #pragma unroll
        for (int nt = 0; nt < 4; ++nt) {
            const __hip_bfloat16* v = vp + (long)nt * 16 * S_;
            vfr[nt][0] = *(const bf16x8*)v;
            vfr[nt][1] = *(const bf16x8*)(v + 32);
        }
    }

    // diagonal tile (kv0 = qt*64), with causal mask
    {
        const int kv0 = qt * 64;
        f32x4 sAcc[4] = {};
        #pragma unroll
        for (int nt = 0; nt < 4; ++nt) {
            sAcc[nt] = __builtin_amdgcn_mfma_f32_16x16x32_bf16(qf0, kf[nt][0], sAcc[nt], 0, 0, 0);
            sAcc[nt] = __builtin_amdgcn_mfma_f32_16x16x32_bf16(qf1, kf[nt][1], sAcc[nt], 0, 0, 0);
        }
        float rmax[4];
        #pragma unroll
        for (int r = 0; r < 4; ++r) rmax[r] = -1e30f;
        #pragma unroll
        for (int nt = 0; nt < 4; ++nt) {
            const int col = kv0 + nt * 16 + l16;
            #pragma unroll
            for (int r = 0; r < 4; ++r) {
                float s = sAcc[nt][r];
                if (col > q_row + r) s = -1e30f;
                sAcc[nt][r] = s;
                rmax[r] = fmaxf(rmax[r], s);
            }
        }
        #pragma unroll
        for (int off = 1; off < 16; off <<= 1)
            #pragma unroll
            for (int r = 0; r < 4; ++r)
                rmax[r] = fmaxf(rmax[r], __shfl_xor(rmax[r], off, 64));

        float alpha[4];
        #pragma unroll
        for (int r = 0; r < 4; ++r) {
            const float mn = fmaxf(m_run[r], rmax[r]);
            alpha[r] = __builtin_exp2f(m_run[r] - mn);
            m_run[r] = mn;
            l_run[r] *= alpha[r];
        }
        #pragma unroll
        for (int nt = 0; nt < 4; ++nt)
            #pragma unroll
            for (int r = 0; r < 4; ++r) {
                const float p = __builtin_exp2f(sAcc[nt][r] - m_run[r]);
                sAcc[nt][r] = p;
                l_run[r] += p;
            }
        #pragma unroll
        for (int nt = 0; nt < 4; ++nt)
            #pragma unroll
            for (int r = 0; r < 4; ++r) o_acc[nt][r] *= alpha[r];

        #pragma unroll
        for (int nt = 0; nt < 4; ++nt)
            #pragma unroll
            for (int r = 0; r < 4; ++r)
                pw[(quad * 4 + r) * 72 + nt * 16 + l16] = (__bf16)sAcc[nt][r];
        asm volatile("" ::: "memory");
        const bf16x8 pf0 = *(const bf16x8*)pb;
        const bf16x8 pf1 = *(const bf16x8*)(pb + 32);
        #pragma unroll
        for (int nt = 0; nt < 4; ++nt) {
            o_acc[nt] = __builtin_amdgcn_mfma_f32_16x16x32_bf16(pf0, vfr[nt][0], o_acc[nt], 0, 0, 0);
            o_acc[nt] = __builtin_amdgcn_mfma_f32_16x16x32_bf16(pf1, vfr[nt][1], o_acc[nt], 0, 0, 0);
        }
    }

    #pragma unroll
    for (int off = 1; off < 16; off <<= 1)
        #pragma unroll
        for (int r = 0; r < 4; ++r)
            l_run[r] += __shfl_xor(l_run[r], off, 64);
    float rl[4];
    #pragma unroll
    for (int r = 0; r < 4; ++r) rl[r] = __builtin_amdgcn_rcpf(l_run[r]);

    #pragma unroll
    for (int nt = 0; nt < 4; ++nt)
        #pragma unroll
        for (int r = 0; r < 4; ++r) {
            const long row = (long)b * S_ + q0 + quad * 4 + r;
            const int col = h * DK_ + nt * 16 + l16;
            Og[row * D_ + col] = __float2bfloat16(o_acc[nt][r] * rl[r]);
        }
}

// ---------------------------------------------------------------------------
__global__ __launch_bounds__(256)
void layernorm_k(const float* __restrict__ in,
                 const __hip_bfloat16* __restrict__ w,
                 const __hip_bfloat16* __restrict__ bb,
                 __hip_bfloat16* __restrict__ out)
{
    const int row = blockIdx.x;
    const int tid = threadIdx.x;
    const float4 v = ((const float4*)(in + (long)row * D_))[tid];
    float s  = v.x + v.y + v.z + v.w;
    float ss = v.x * v.x + v.y * v.y + v.z * v.z + v.w * v.w;
    #pragma unroll
    for (int off = 1; off < 64; off <<= 1) {
        s  += __shfl_xor(s, off, 64);
        ss += __shfl_xor(ss, off, 64);
    }
    __shared__ float red[8];
    if ((tid & 63) == 0) { red[tid >> 6] = s; red[4 + (tid >> 6)] = ss; }
    __syncthreads();
    s  = red[0] + red[1] + red[2] + red[3];
    ss = red[4] + red[5] + red[6] + red[7];
    const float mean = s * (1.f / D_);
    const float var  = ss * (1.f / D_) - mean * mean;
    const float rs = rsqrtf(var + 1e-5f);
    const int d0 = tid * 4;
    const float xs[4] = { v.x, v.y, v.z, v.w };
    #pragma unroll
    for (int j = 0; j < 4; ++j) {
        const float wv = __bfloat162float(w[d0 + j]);
        const float bv = __bfloat162float(bb[d0 + j]);
        out[(long)row * D_ + d0 + j] = __float2bfloat16((xs[j] - mean) * rs * wv + bv);
    }
}

__global__ __launch_bounds__(256)
void embed_k(const int* __restrict__ idx,
             const __hip_bfloat16* __restrict__ emb,
             __hip_bfloat16* __restrict__ X)
{
    const int row = blockIdx.x;
    const int s = row & (S_ - 1);
    const int tid = threadIdx.x;
    const int token = idx[row];
    const __hip_bfloat16* e = emb + (long)token * D_;
    #pragma unroll
    for (int j = 0; j < 4; ++j) {
        const int d = tid + j * 256;
        const float di = (float)(d & ~1);
        const float freq = __expf(di * (-9.210340371976184f / (float)D_));
        const float angle = (float)s * freq;
        const float pe = (d & 1) ? cosf(angle) : sinf(angle);
        X[(long)row * D_ + d] = __float2bfloat16(__bfloat162float(e[d]) + pe);
    }
}

// ---------------------------------------------------------------------------
extern "C" void kernel_launch(void* const* d_in, const int* in_sizes, int n_in,
                              void* d_out, int out_size, void* d_ws, size_t ws_size,
                              hipStream_t stream)
{
    const int* indices = (const int*)d_in[0];
    const unsigned short* probe = (const unsigned short*)d_in[6];  // ln1_w (ones)

    const long NTOK = (long)B_ * S_;   // 4096
    char* ws = (char*)d_ws;
    __hip_bfloat16* X  = (__hip_bfloat16*)ws; ws += NTOK * D_ * 2;
    __hip_bfloat16* Qb = (__hip_bfloat16*)ws; ws += NTOK * D_ * 2;
    __hip_bfloat16* Kb = (__hip_bfloat16*)ws; ws += NTOK * D_ * 2;
    __hip_bfloat16* VT = (__hip_bfloat16*)ws; ws += NTOK * D_ * 2;   // [B][H][DK][S]
    __hip_bfloat16* Ob = (__hip_bfloat16*)ws; ws += NTOK * D_ * 2;
    __hip_bfloat16* Hb = Qb;  // FFN hidden aliases Qb..Ob, disjoint lifetime
    float* tmp = (float*)ws;                  ws += NTOK * D_ * 4;
    __hip_bfloat16* cEmb  = (__hip_bfloat16*)ws; ws += (long)V_ * D_ * 2;
    __hip_bfloat16* cWq   = (__hip_bfloat16*)ws; ws += (long)L_ * D_ * D_ * 2;
    __hip_bfloat16* cWk   = (__hip_bfloat16*)ws; ws += (long)L_ * D_ * D_ * 2;
    __hip_bfloat16* cWv   = (__hip_bfloat16*)ws; ws += (long)L_ * D_ * D_ * 2;
    __hip_bfloat16* cWo   = (__hip_bfloat16*)ws; ws += (long)L_ * D_ * D_ * 2;
    __hip_bfloat16* cW1   = (__hip_bfloat16*)ws; ws += (long)L_ * DFF_ * D_ * 2;
    __hip_bfloat16* cW2   = (__hip_bfloat16*)ws; ws += (long)L_ * D_ * DFF_ * 2;
    __hip_bfloat16* cWout = (__hip_bfloat16*)ws; ws += (long)V_ * D_ * 2;
    __hip_bfloat16* cLn1w = (__hip_bfloat16*)ws; ws += (long)L_ * D_ * 2;
    __hip_bfloat16* cLn1b = (__hip_bfloat16*)ws; ws += (long)L_ * D_ * 2;
    __hip_bfloat16* cLn2w = (__hip_bfloat16*)ws; ws += (long)L_ * D_ * 2;
    __hip_bfloat16* cLn2b = (__hip_bfloat16*)ws; ws += (long)L_ * D_ * 2;

    struct { const void* src; __hip_bfloat16* dst; long n; } cv[12] = {
        { d_in[1],  cEmb,  (long)V_ * D_ },
        { d_in[2],  cWq,   (long)L_ * D_ * D_ },
        { d_in[3],  cWk,   (long)L_ * D_ * D_ },
        { d_in[4],  cWv,   (long)L_ * D_ * D_ },
        { d_in[5],  cWo,   (long)L_ * D_ * D_ },
        { d_in[6],  cLn1w, (long)L_ * D_ },
        { d_in[7],  cLn1b, (long)L_ * D_ },
        { d_in[8],  cW1,   (long)L_ * DFF_ * D_ },
        { d_in[9],  cW2,   (long)L_ * D_ * DFF_ },
        { d_in[10], cLn2w, (long)L_ * D_ },
        { d_in[11], cLn2b, (long)L_ * D_ },
        { d_in[12], cWout, (long)V_ * D_ },
    };
    for (int i = 0; i < 12; ++i) {
        const long blocks = (cv[i].n + 2047) / 2048;
        canon_k<<<dim3((unsigned)blocks), 256, 0, stream>>>(cv[i].src, cv[i].dst, cv[i].n, probe);
    }

    embed_k<<<dim3(NTOK), 256, 0, stream>>>(indices, cEmb, X);

    for (int l = 0; l < L_; ++l) {
        const __hip_bfloat16* wq = cWq + (long)l * D_ * D_;
        const __hip_bfloat16* wk = cWk + (long)l * D_ * D_;
        const __hip_bfloat16* wv = cWv + (long)l * D_ * D_;
        const __hip_bfloat16* wo = cWo + (long)l * D_ * D_;
        const __hip_bfloat16* w1 = cW1 + (long)l * DFF_ * D_;
        const __hip_bfloat16* w2 = cW2 + (long)l * D_ * DFF_;

        gemm_bt<5, 128><<<dim3(32, 8, 3), 256, 0, stream>>>(X, wq, wk, wv, Qb, Kb, VT, nullptr, nullptr, 4096, 1024, 1024);
        flash_attn<<<dim3(32, 16, 2), 256, 0, stream>>>(Qb, Kb, VT, Ob);
        gemm_bt<1, 64><<<dim3(64, 8, 1), 256, 0, stream>>>(Ob, wo, wo, wo, tmp, tmp, tmp, X, nullptr, 4096, 1024, 1024);
        layernorm_k<<<dim3(4096), 256, 0, stream>>>(tmp, cLn1w + l * D_, cLn1b + l * D_, X);
        gemm_bt<2, 128><<<dim3(32, 32, 1), 256, 0, stream>>>(X, w1, w1, w1, Hb, Hb, Hb, nullptr, nullptr, 4096, 4096, 1024);
        gemm_bt<1, 64><<<dim3(64, 8, 1), 256, 0, stream>>>(Hb, w2, w2, w2, tmp, tmp, tmp, X, nullptr, 4096, 1024, 4096);
        layernorm_k<<<dim3(4096), 256, 0, stream>>>(tmp, cLn2w + l * D_, cLn2b + l * D_, X);
    }

    gemm_bt<3, 128><<<dim3(32, 16, 1), 256, 0, stream>>>(X, cWout, cWout, cWout, d_out, d_out, d_out, nullptr, probe, 4096, V_, 1024);
}